// Round 11
// baseline (416.195 us; speedup 1.0000x reference)
//
#include <hip/hip_runtime.h>
#include <hip/hip_cooperative_groups.h>
#include <hip/hip_bf16.h>
#include <math.h>

namespace cg = cooperative_groups;

#define BB 2
#define SS 2048
#define DD 1024
#define HH 16
#define HDIM 64

typedef unsigned short u16;
typedef __attribute__((ext_vector_type(8))) short bfrag;   // 8 bf16 = 4 VGPRs
typedef __attribute__((ext_vector_type(4))) float f32x4;

#define NEG_BIG (-1e30f)
// 1/sqrt(64) * log2(e): folded into Q so attention uses exp2 directly
#define QSCALE 0.18033688011112042f

__device__ __forceinline__ u16 f2u(float f) {
    unsigned int u = __builtin_bit_cast(unsigned int, f);
    u += 0x7fffu + ((u >> 16) & 1u);
    return (u16)(u >> 16);
}

__device__ __forceinline__ void async16(const u16* g, u16* l) {
    __builtin_amdgcn_global_load_lds((__attribute__((address_space(1))) void*)g,
                                     (__attribute__((address_space(3))) void*)l,
                                     16, 0, 0);
}

__device__ __forceinline__ f32x4 mfma16(bfrag a, bfrag b, f32x4 c) {
    return __builtin_amdgcn_mfma_f32_16x16x32_bf16(a, b, c, 0, 0, 0);
}

// ===========================================================================
// FUSED cooperative kernel: prep -> qkv -> attn -> out, grid.sync between.
// LDS: 40960 B union (max stage need). launch_bounds(256,4) -> VGPR<=128,
// 40KB LDS -> 4 blocks/CU -> grid 1024 co-resident.
// ===========================================================================
__global__ __launch_bounds__(256, 4) void fused_k(
    const float* __restrict__ x,
    const float* __restrict__ wq, const float* __restrict__ wk,
    const float* __restrict__ wv, const float* __restrict__ wo,
    const float* __restrict__ bo,
    u16* __restrict__ xb, u16* __restrict__ wT,
    u16* __restrict__ Qb, u16* __restrict__ Kb, u16* __restrict__ Vt,
    float* __restrict__ out)
{
    cg::grid_group grid = cg::this_grid();
    __shared__ __align__(16) u16 smem[20480];    // 40 KB
    const int t = threadIdx.x;
    const int gsz = (int)gridDim.x;
    const int lane15 = t & 15, quad = (t >> 4) & 3, wave = t >> 6;

    // ---------------- stage 0: prep (x cvt + weight transpose) --------------
    for (int id = blockIdx.x; id < 3072; id += gsz) {
        if (id < 2048) {
            int i = (id * 256 + t) * 8;
            float4 a = *(const float4*)(x + i);
            float4 b = *(const float4*)(x + i + 4);
            u16 o8[8] = { f2u(a.x), f2u(a.y), f2u(a.z), f2u(a.w),
                          f2u(b.x), f2u(b.y), f2u(b.z), f2u(b.w) };
            *(uint4*)(xb + i) = *(uint4*)o8;
        } else {
            const int wid = id - 2048;
            const int z = wid >> 8;
            const int ktt = wid & 15, ntt = (wid >> 4) & 15;
            const float* w = (z == 0) ? wq : (z == 1) ? wk : (z == 2) ? wv : wo;
            u16* o = wT + (size_t)z * DD * DD;
            u16 (*T)[72] = (u16(*)[72])smem;      // 64x72 = 9216 B
            const int k0 = ktt * 64, n0 = ntt * 64;
            {
                int kr = t >> 2, nbs = (t & 3) * 16;
                const float4* s4 = (const float4*)(w + (size_t)(k0 + kr) * DD + n0 + nbs);
                #pragma unroll
                for (int jj = 0; jj < 4; ++jj) {
                    float4 v = s4[jj];
                    T[kr][nbs + jj*4 + 0] = f2u(v.x);
                    T[kr][nbs + jj*4 + 1] = f2u(v.y);
                    T[kr][nbs + jj*4 + 2] = f2u(v.z);
                    T[kr][nbs + jj*4 + 3] = f2u(v.w);
                }
            }
            __syncthreads();
            {
                int nr = t >> 2, kb2 = (t & 3) * 16;
                u16 tmp[16];
                #pragma unroll
                for (int j = 0; j < 16; ++j) tmp[j] = T[kb2 + j][nr];
                *(uint4*)(o + (size_t)(n0 + nr) * DD + k0 + kb2)     = ((uint4*)tmp)[0];
                *(uint4*)(o + (size_t)(n0 + nr) * DD + k0 + kb2 + 8) = ((uint4*)tmp)[1];
            }
        }
        __syncthreads();
    }
    grid.sync();

    // ---------------- stage 1: QKV GEMM (BK=64, 32 MFMA/barrier) -------------
    for (int id = blockIdx.x; id < 768; id += gsz) {
        const int z = id >> 8;
        const int m0 = (id & 31) * 128, n0 = ((id >> 5) & 7) * 128;
        const u16* wTz = wT + (size_t)z * DD * DD;
        const float osc = (z == 0) ? QSCALE : 1.0f;
        u16* As = smem;              // 8192 u16
        u16* Bs = smem + 8192;       // 8192 u16
        const int wm = wave & 1, wn = wave >> 1;

        int srow[4], scol[4];
        #pragma unroll
        for (int i = 0; i < 4; ++i) {
            int c = t + i * 256;
            srow[i] = c >> 3;
            scol[i] = (c & 7) ^ (srow[i] & 7);
        }
        const int ldb = (t & 192) * 8;

        int aoff[4][2], boff[4][2];
        #pragma unroll
        for (int mi = 0; mi < 4; ++mi) {
            int r = wm * 64 + mi * 16 + lane15;
            #pragma unroll
            for (int kh = 0; kh < 2; ++kh)
                aoff[mi][kh] = (r * 8 + ((kh * 4 + quad) ^ (r & 7))) * 8;
        }
        #pragma unroll
        for (int ni = 0; ni < 4; ++ni) {
            int r = wn * 64 + ni * 16 + lane15;
            #pragma unroll
            for (int kh = 0; kh < 2; ++kh)
                boff[ni][kh] = (r * 8 + ((kh * 4 + quad) ^ (r & 7))) * 8;
        }

        f32x4 acc[4][4];
        #pragma unroll
        for (int mi = 0; mi < 4; ++mi)
            #pragma unroll
            for (int ni = 0; ni < 4; ++ni)
                acc[mi][ni] = (f32x4){0.f, 0.f, 0.f, 0.f};

        for (int it = 0; it < 16; ++it) {
            const int k0 = it * 64;
            #pragma unroll
            for (int i = 0; i < 4; ++i) {
                async16(xb  + (size_t)(m0 + srow[i]) * DD + k0 + scol[i] * 8,
                        As + ldb + i * 2048);
                async16(wTz + (size_t)(n0 + srow[i]) * DD + k0 + scol[i] * 8,
                        Bs + ldb + i * 2048);
            }
            __syncthreads();
            #pragma unroll
            for (int kh = 0; kh < 2; ++kh) {
                bfrag av[4], bv[4];
                #pragma unroll
                for (int mi = 0; mi < 4; ++mi) av[mi] = *(const bfrag*)(As + aoff[mi][kh]);
                #pragma unroll
                for (int ni = 0; ni < 4; ++ni) bv[ni] = *(const bfrag*)(Bs + boff[ni][kh]);
                #pragma unroll
                for (int mi = 0; mi < 4; ++mi)
                    #pragma unroll
                    for (int ni = 0; ni < 4; ++ni)
                        acc[mi][ni] = mfma16(av[mi], bv[ni], acc[mi][ni]);
            }
            __syncthreads();
        }

        if (z != 2) {
            u16* o = (z == 0) ? Qb : Kb;
            #pragma unroll
            for (int mi = 0; mi < 4; ++mi) {
                #pragma unroll
                for (int r = 0; r < 4; ++r) {
                    int m = m0 + wm * 64 + mi * 16 + quad * 4 + r;
                    int b = m >> 11, s = m & (SS - 1);
                    #pragma unroll
                    for (int ni = 0; ni < 4; ++ni) {
                        int n = n0 + wn * 64 + ni * 16 + lane15;
                        int h = n >> 6, hd = n & 63;
                        o[(((size_t)(b * HH + h)) * SS + s) * HDIM + hd] = f2u(acc[mi][ni][r] * osc);
                    }
                }
            }
            __syncthreads();
        } else {
            u16* T = smem;
            const int bq = m0 >> 11;
            const int ms = m0 & (SS - 1);
            #pragma unroll
            for (int hh = 0; hh < 2; ++hh) {
                if (wn == hh) {
                    #pragma unroll
                    for (int mi = 0; mi < 4; ++mi)
                        #pragma unroll
                        for (int r = 0; r < 4; ++r) {
                            int ml = wm * 64 + mi * 16 + quad * 4 + r;
                            #pragma unroll
                            for (int ni = 0; ni < 4; ++ni) {
                                int nl = ni * 16 + lane15;
                                T[nl * 128 + (ml ^ ((nl & 7) << 4))] = f2u(acc[mi][ni][r]);
                            }
                        }
                }
                __syncthreads();
                const int h = (n0 >> 6) + hh;
                u16* dst = Vt + ((size_t)(bq * HH + h)) * (HDIM * SS);
                #pragma unroll
                for (int i = 0; i < 4; ++i) {
                    int c = t + i * 256;
                    int row = c >> 4;
                    int mb  = (c & 15) * 8;
                    uint4 val = *(const uint4*)&T[row * 128 + (mb ^ ((row & 7) << 4))];
                    *(uint4*)(dst + (size_t)row * SS + ms + mb) = val;
                }
                __syncthreads();
            }
        }
    }
    grid.sync();

    // ---------------- stage 2: flash attention ------------------------------
    // vid -> (bh, qt) balanced so each CU's 4 resident blocks sum to ~62 tiles
    for (int id = blockIdx.x; id < 1024; id += gsz) {
        const int kk = id >> 8, j = id & 255;
        const int bh = j >> 3, p = j & 7;
        const int qt = kk * 8 + ((kk & 1) ? (7 - p) : p);
        const int q0 = qt * 64;
        const int b = bh >> 4, h = bh & 15;

        const u16* Qp = Qb + (size_t)bh * SS * HDIM;
        const u16* Kp = Kb + (size_t)bh * SS * HDIM;
        const u16* Vp = Vt + (size_t)bh * HDIM * SS;
        u16* QP = smem;                        // 4096 u16
        // Ks[cb] = smem + 4096 + cb*4096 ; Vs[cb] = smem + 12288 + cb*4096

        const int kr0 = t >> 3,         ks0 = t & 7;
        const int kr1 = (t + 256) >> 3, ks1 = (t + 256) & 7;
        const int kc0 = ks0 ^ (kr0 & 7);
        const int kc1 = ks1 ^ (kr1 & 7);
        const int ldst = (t & 192) * 8;

        async16(Qp + (size_t)(q0 + kr0) * HDIM + kc0 * 8, QP + ldst);
        async16(Qp + (size_t)(q0 + kr1) * HDIM + kc1 * 8, QP + ldst + 2048);
        async16(Kp + (size_t)kr0 * HDIM + kc0 * 8, smem + 4096 + ldst);
        async16(Kp + (size_t)kr1 * HDIM + kc1 * 8, smem + 4096 + ldst + 2048);
        async16(Vp + (size_t)kr0 * SS + kc0 * 8, smem + 12288 + ldst);
        async16(Vp + (size_t)kr1 * SS + kc1 * 8, smem + 12288 + ldst + 2048);

        const int qrow = wave * 16 + lane15;
        int qoff[2], koff[4][2];
        #pragma unroll
        for (int kh = 0; kh < 2; ++kh)
            qoff[kh] = (qrow * 8 + ((kh * 4 + quad) ^ (qrow & 7))) * 8;
        #pragma unroll
        for (int ni = 0; ni < 4; ++ni)
            #pragma unroll
            for (int kh = 0; kh < 2; ++kh) {
                int row = ni * 16 + lane15;
                koff[ni][kh] = (row * 8 + ((kh * 4 + quad) ^ (row & 7))) * 8;
            }

        __syncthreads();
        bfrag aq[2];
        aq[0] = *(const bfrag*)(QP + qoff[0]);
        aq[1] = *(const bfrag*)(QP + qoff[1]);
        __syncthreads();

        f32x4 acc_o[4];
        float rsum[4] = {0.f, 0.f, 0.f, 0.f};
        #pragma unroll
        for (int nd = 0; nd < 4; ++nd) acc_o[nd] = (f32x4){0.f, 0.f, 0.f, 0.f};

        const int qgb = q0 + wave * 16 + quad * 4;

        for (int kt = 0; kt <= qt; ++kt) {
            if (kt < qt) {
                const int nv0 = (kt + 1) * 64;
                const int pb = (kt + 1) & 1;
                async16(Kp + (size_t)(nv0 + kr0) * HDIM + kc0 * 8, smem + 4096 + pb * 4096 + ldst);
                async16(Kp + (size_t)(nv0 + kr1) * HDIM + kc1 * 8, smem + 4096 + pb * 4096 + ldst + 2048);
                async16(Vp + (size_t)kr0 * SS + nv0 + kc0 * 8, smem + 12288 + pb * 4096 + ldst);
                async16(Vp + (size_t)kr1 * SS + nv0 + kc1 * 8, smem + 12288 + pb * 4096 + ldst + 2048);
            }
            const u16* ksb = smem + 4096 + (kt & 1) * 4096;
            const u16* vsb = smem + 12288 + (kt & 1) * 4096;
            const int kv0 = kt * 64;

            f32x4 s_acc[4];
            #pragma unroll
            for (int ni = 0; ni < 4; ++ni) s_acc[ni] = (f32x4){0.f, 0.f, 0.f, 0.f};
            #pragma unroll
            for (int kh = 0; kh < 2; ++kh)
                #pragma unroll
                for (int ni = 0; ni < 4; ++ni)
                    s_acc[ni] = mfma16(aq[kh], *(const bfrag*)(ksb + koff[ni][kh]), s_acc[ni]);

            const bool diag = (kt == qt);
            #pragma unroll
            for (int ni = 0; ni < 4; ++ni) {
                int kvg = kv0 + ni * 16 + lane15;
                #pragma unroll
                for (int r = 0; r < 4; ++r) {
                    float v = s_acc[ni][r];
                    if (diag && (kvg > qgb + r)) v = NEG_BIG;
                    float pw = exp2f(v);
                    unsigned pu = __builtin_bit_cast(unsigned, pw);
                    rsum[r] += __builtin_bit_cast(float, pu & 0xffff0000u);
                    int row = wave * 16 + quad * 4 + r;
                    int col = ni * 16 + lane15;
                    QP[(row * 8 + ((col >> 3) ^ (row & 7))) * 8 + (col & 7)] = (u16)(pu >> 16);
                }
            }

            #pragma unroll
            for (int kh = 0; kh < 2; ++kh) {
                bfrag ap = *(const bfrag*)(QP + qoff[kh]);
                #pragma unroll
                for (int nd = 0; nd < 4; ++nd)
                    acc_o[nd] = mfma16(ap, *(const bfrag*)(vsb + koff[nd][kh]), acc_o[nd]);
            }
            __syncthreads();
        }

        #pragma unroll
        for (int off = 1; off < 16; off <<= 1)
            #pragma unroll
            for (int r = 0; r < 4; ++r)
                rsum[r] += __shfl_xor(rsum[r], off, 64);

        #pragma unroll
        for (int r = 0; r < 4; ++r) {
            float inv = 1.f / rsum[r];
            int srw = q0 + wave * 16 + quad * 4 + r;
            size_t base = ((size_t)b * SS + srw) * DD + h * HDIM;
            #pragma unroll
            for (int nd = 0; nd < 4; ++nd)
                xb[base + nd * 16 + lane15] = f2u(acc_o[nd][r] * inv);  // ctx -> xb region
        }
        __syncthreads();
    }
    grid.sync();

    // ---------------- stage 3: out projection -------------------------------
    for (int id = blockIdx.x; id < 512; id += gsz) {
        const int m0 = (id & 31) * 128, n0 = (id >> 5) * 64;
        const u16* woT = wT + (size_t)3 * DD * DD;
        u16* As = smem;              // 8192 u16
        u16* Bs = smem + 8192;       // 4096 u16
        const int wm = wave & 1, wn = wave >> 1;

        int srow[4], scol[4];
        #pragma unroll
        for (int i = 0; i < 4; ++i) {
            int c = t + i * 256;
            srow[i] = c >> 3;
            scol[i] = (c & 7) ^ (srow[i] & 7);
        }
        const int ldb = (t & 192) * 8;

        int aoff[4][2], boff[2][2];
        #pragma unroll
        for (int mi = 0; mi < 4; ++mi) {
            int r = wm * 64 + mi * 16 + lane15;
            #pragma unroll
            for (int kh = 0; kh < 2; ++kh)
                aoff[mi][kh] = (r * 8 + ((kh * 4 + quad) ^ (r & 7))) * 8;
        }
        #pragma unroll
        for (int ni = 0; ni < 2; ++ni) {
            int r = wn * 32 + ni * 16 + lane15;
            #pragma unroll
            for (int kh = 0; kh < 2; ++kh)
                boff[ni][kh] = (r * 8 + ((kh * 4 + quad) ^ (r & 7))) * 8;
        }

        f32x4 acc[4][2];
        #pragma unroll
        for (int mi = 0; mi < 4; ++mi)
            #pragma unroll
            for (int ni = 0; ni < 2; ++ni)
                acc[mi][ni] = (f32x4){0.f, 0.f, 0.f, 0.f};

        for (int it = 0; it < 16; ++it) {
            const int k0 = it * 64;
            #pragma unroll
            for (int i = 0; i < 4; ++i)
                async16(xb + (size_t)(m0 + srow[i]) * DD + k0 + scol[i] * 8,
                        As + ldb + i * 2048);
            #pragma unroll
            for (int i = 0; i < 2; ++i)
                async16(woT + (size_t)(n0 + srow[i]) * DD + k0 + scol[i] * 8,
                        Bs + ldb + i * 2048);
            __syncthreads();
            #pragma unroll
            for (int kh = 0; kh < 2; ++kh) {
                bfrag av[4], bv[2];
                #pragma unroll
                for (int mi = 0; mi < 4; ++mi) av[mi] = *(const bfrag*)(As + aoff[mi][kh]);
                #pragma unroll
                for (int ni = 0; ni < 2; ++ni) bv[ni] = *(const bfrag*)(Bs + boff[ni][kh]);
                #pragma unroll
                for (int mi = 0; mi < 4; ++mi)
                    #pragma unroll
                    for (int ni = 0; ni < 2; ++ni)
                        acc[mi][ni] = mfma16(av[mi], bv[ni], acc[mi][ni]);
            }
            __syncthreads();
        }

        float bias[2];
        #pragma unroll
        for (int ni = 0; ni < 2; ++ni)
            bias[ni] = bo[n0 + wn * 32 + ni * 16 + lane15];

        #pragma unroll
        for (int mi = 0; mi < 4; ++mi) {
            #pragma unroll
            for (int r = 0; r < 4; ++r) {
                int m = m0 + wm * 64 + mi * 16 + quad * 4 + r;
                #pragma unroll
                for (int ni = 0; ni < 2; ++ni) {
                    int n = n0 + wn * 32 + ni * 16 + lane15;
                    out[(size_t)m * DD + n] = acc[mi][ni][r] + bias[ni];
                }
            }
        }
    }
}

// ===========================================================================
// FALLBACK path: round-10 four-kernel pipeline (used only if cooperative
// launch is rejected, e.g. by graph capture).
// ===========================================================================
__global__ __launch_bounds__(256) void prep_k(
    const float* __restrict__ x,  u16* __restrict__ xb,
    const float* __restrict__ wq, const float* __restrict__ wk,
    const float* __restrict__ wv, const float* __restrict__ wo,
    u16* __restrict__ wT)
{
    const int id = blockIdx.x;
    const int t = threadIdx.x;
    if (id < 2048) {
        int i = (id * 256 + t) * 8;
        float4 a = *(const float4*)(x + i);
        float4 b = *(const float4*)(x + i + 4);
        u16 o[8] = { f2u(a.x), f2u(a.y), f2u(a.z), f2u(a.w),
                     f2u(b.x), f2u(b.y), f2u(b.z), f2u(b.w) };
        *(uint4*)(xb + i) = *(uint4*)o;
        return;
    }
    const int wid = id - 2048;
    const int z = wid >> 8;
    const int kt = wid & 15, nt = (wid >> 4) & 15;
    const float* w = (z == 0) ? wq : (z == 1) ? wk : (z == 2) ? wv : wo;
    u16* o = wT + (size_t)z * DD * DD;
    __shared__ __align__(16) u16 T[64][72];
    const int k0 = kt * 64, n0 = nt * 64;
    {
        int kr = t >> 2, nb = (t & 3) * 16;
        const float4* s4 = (const float4*)(w + (size_t)(k0 + kr) * DD + n0 + nb);
        #pragma unroll
        for (int jj = 0; jj < 4; ++jj) {
            float4 v = s4[jj];
            T[kr][nb + jj*4 + 0] = f2u(v.x);
            T[kr][nb + jj*4 + 1] = f2u(v.y);
            T[kr][nb + jj*4 + 2] = f2u(v.z);
            T[kr][nb + jj*4 + 3] = f2u(v.w);
        }
    }
    __syncthreads();
    {
        int nr = t >> 2, kb = (t & 3) * 16;
        u16 tmp[16];
        #pragma unroll
        for (int j = 0; j < 16; ++j) tmp[j] = T[kb + j][nr];
        *(uint4*)(o + (size_t)(n0 + nr) * DD + k0 + kb)     = ((uint4*)tmp)[0];
        *(uint4*)(o + (size_t)(n0 + nr) * DD + k0 + kb + 8) = ((uint4*)tmp)[1];
    }
}

__global__ __launch_bounds__(256) void gemm_qkv_k(
    const u16* __restrict__ xb, const u16* __restrict__ wT,
    u16* __restrict__ Qo, u16* __restrict__ Ko, u16* __restrict__ Vt)
{
    const u16* wTz = wT + (size_t)blockIdx.z * DD * DD;
    const float osc = (blockIdx.z == 0) ? QSCALE : 1.0f;
    __shared__ __align__(16) u16 As[128 * 64];
    __shared__ __align__(16) u16 Bs[128 * 64];
    const int t = threadIdx.x;
    const int m0 = blockIdx.x * 128, n0 = blockIdx.y * 128;
    const int lane15 = t & 15, quad = (t >> 4) & 3, wave = t >> 6;
    const int wm = wave & 1, wn = wave >> 1;
    int srow[4], scol[4];
    #pragma unroll
    for (int i = 0; i < 4; ++i) {
        int c = t + i * 256;
        srow[i] = c >> 3;
        scol[i] = (c & 7) ^ (srow[i] & 7);
    }
    const int ldb = (t & 192) * 8;
    int aoff[4][2], boff[4][2];
    #pragma unroll
    for (int mi = 0; mi < 4; ++mi) {
        int r = wm * 64 + mi * 16 + lane15;
        #pragma unroll
        for (int kh = 0; kh < 2; ++kh)
            aoff[mi][kh] = (r * 8 + ((kh * 4 + quad) ^ (r & 7))) * 8;
    }
    #pragma unroll
    for (int ni = 0; ni < 4; ++ni) {
        int r = wn * 64 + ni * 16 + lane15;
        #pragma unroll
        for (int kh = 0; kh < 2; ++kh)
            boff[ni][kh] = (r * 8 + ((kh * 4 + quad) ^ (r & 7))) * 8;
    }
    f32x4 acc[4][4];
    #pragma unroll
    for (int mi = 0; mi < 4; ++mi)
        #pragma unroll
        for (int ni = 0; ni < 4; ++ni)
            acc[mi][ni] = (f32x4){0.f, 0.f, 0.f, 0.f};
    for (int it = 0; it < 16; ++it) {
        const int k0 = it * 64;
        #pragma unroll
        for (int i = 0; i < 4; ++i) {
            async16(xb  + (size_t)(m0 + srow[i]) * DD + k0 + scol[i] * 8, As + ldb + i * 2048);
            async16(wTz + (size_t)(n0 + srow[i]) * DD + k0 + scol[i] * 8, Bs + ldb + i * 2048);
        }
        __syncthreads();
        #pragma unroll
        for (int kh = 0; kh < 2; ++kh) {
            bfrag av[4], bv[4];
            #pragma unroll
            for (int mi = 0; mi < 4; ++mi) av[mi] = *(const bfrag*)(As + aoff[mi][kh]);
            #pragma unroll
            for (int ni = 0; ni < 4; ++ni) bv[ni] = *(const bfrag*)(Bs + boff[ni][kh]);
            #pragma unroll
            for (int mi = 0; mi < 4; ++mi)
                #pragma unroll
                for (int ni = 0; ni < 4; ++ni)
                    acc[mi][ni] = mfma16(av[mi], bv[ni], acc[mi][ni]);
        }
        __syncthreads();
    }
    if (blockIdx.z != 2) {
        u16* out = (blockIdx.z == 0) ? Qo : Ko;
        #pragma unroll
        for (int mi = 0; mi < 4; ++mi)
            #pragma unroll
            for (int r = 0; r < 4; ++r) {
                int m = m0 + wm * 64 + mi * 16 + quad * 4 + r;
                int b = m >> 11, s = m & (SS - 1);
                #pragma unroll
                for (int ni = 0; ni < 4; ++ni) {
                    int n = n0 + wn * 64 + ni * 16 + lane15;
                    int h = n >> 6, hd = n & 63;
                    out[(((size_t)(b * HH + h)) * SS + s) * HDIM + hd] = f2u(acc[mi][ni][r] * osc);
                }
            }
    } else {
        u16* T = As;
        const int bq = m0 >> 11;
        const int ms = m0 & (SS - 1);
        #pragma unroll
        for (int hh = 0; hh < 2; ++hh) {
            if (wn == hh) {
                #pragma unroll
                for (int mi = 0; mi < 4; ++mi)
                    #pragma unroll
                    for (int r = 0; r < 4; ++r) {
                        int ml = wm * 64 + mi * 16 + quad * 4 + r;
                        #pragma unroll
                        for (int ni = 0; ni < 4; ++ni) {
                            int nl = ni * 16 + lane15;
                            T[nl * 128 + (ml ^ ((nl & 7) << 4))] = f2u(acc[mi][ni][r]);
                        }
                    }
            }
            __syncthreads();
            const int h = (n0 >> 6) + hh;
            u16* dst = Vt + ((size_t)(bq * HH + h)) * (HDIM * SS);
            #pragma unroll
            for (int i = 0; i < 4; ++i) {
                int c = t + i * 256;
                int row = c >> 4;
                int mb  = (c & 15) * 8;
                uint4 val = *(const uint4*)&T[row * 128 + (mb ^ ((row & 7) << 4))];
                *(uint4*)(dst + (size_t)row * SS + ms + mb) = val;
            }
            __syncthreads();
        }
    }
}

__global__ __launch_bounds__(256) void gemm_out_k(
    const u16* __restrict__ ctxb, const u16* __restrict__ woT,
    const float* __restrict__ bo, float* __restrict__ out)
{
    __shared__ __align__(16) u16 As[128 * 64];
    __shared__ __align__(16) u16 Bs[64 * 64];
    const int t = threadIdx.x;
    const int m0 = blockIdx.x * 128, n0 = blockIdx.y * 64;
    const int lane15 = t & 15, quad = (t >> 4) & 3, wave = t >> 6;
    const int wm = wave & 1, wn = wave >> 1;
    int srow[4], scol[4];
    #pragma unroll
    for (int i = 0; i < 4; ++i) {
        int c = t + i * 256;
        srow[i] = c >> 3;
        scol[i] = (c & 7) ^ (srow[i] & 7);
    }
    const int ldb = (t & 192) * 8;
    int aoff[4][2], boff[2][2];
    #pragma unroll
    for (int mi = 0; mi < 4; ++mi) {
        int r = wm * 64 + mi * 16 + lane15;
        #pragma unroll
        for (int kh = 0; kh < 2; ++kh)
            aoff[mi][kh] = (r * 8 + ((kh * 4 + quad) ^ (r & 7))) * 8;
    }
    #pragma unroll
    for (int ni = 0; ni < 2; ++ni) {
        int r = wn * 32 + ni * 16 + lane15;
        #pragma unroll
        for (int kh = 0; kh < 2; ++kh)
            boff[ni][kh] = (r * 8 + ((kh * 4 + quad) ^ (r & 7))) * 8;
    }
    f32x4 acc[4][2];
    #pragma unroll
    for (int mi = 0; mi < 4; ++mi)
        #pragma unroll
        for (int ni = 0; ni < 2; ++ni)
            acc[mi][ni] = (f32x4){0.f, 0.f, 0.f, 0.f};
    for (int it = 0; it < 16; ++it) {
        const int k0 = it * 64;
        #pragma unroll
        for (int i = 0; i < 4; ++i)
            async16(ctxb + (size_t)(m0 + srow[i]) * DD + k0 + scol[i] * 8, As + ldb + i * 2048);
        #pragma unroll
        for (int i = 0; i < 2; ++i)
            async16(woT + (size_t)(n0 + srow[i]) * DD + k0 + scol[i] * 8, Bs + ldb + i * 2048);
        __syncthreads();
        #pragma unroll
        for (int kh = 0; kh < 2; ++kh) {
            bfrag av[4], bv[2];
            #pragma unroll
            for (int mi = 0; mi < 4; ++mi) av[mi] = *(const bfrag*)(As + aoff[mi][kh]);
            #pragma unroll
            for (int ni = 0; ni < 2; ++ni) bv[ni] = *(const bfrag*)(Bs + boff[ni][kh]);
            #pragma unroll
            for (int mi = 0; mi < 4; ++mi)
                #pragma unroll
                for (int ni = 0; ni < 2; ++ni)
                    acc[mi][ni] = mfma16(av[mi], bv[ni], acc[mi][ni]);
        }
        __syncthreads();
    }
    float bias[2];
    #pragma unroll
    for (int ni = 0; ni < 2; ++ni)
        bias[ni] = bo[n0 + wn * 32 + ni * 16 + lane15];
    #pragma unroll
    for (int mi = 0; mi < 4; ++mi)
        #pragma unroll
        for (int r = 0; r < 4; ++r) {
            int m = m0 + wm * 64 + mi * 16 + quad * 4 + r;
            #pragma unroll
            for (int ni = 0; ni < 2; ++ni) {
                int n = n0 + wn * 32 + ni * 16 + lane15;
                out[(size_t)m * DD + n] = acc[mi][ni][r] + bias[ni];
            }
        }
}

__global__ __launch_bounds__(256, 4) void attn_k(
    const u16* __restrict__ Q, const u16* __restrict__ K,
    const u16* __restrict__ Vt, u16* __restrict__ ctx)
{
    __shared__ __align__(16) u16 QP[64 * 64];
    __shared__ __align__(16) u16 Ks[2][64 * 64];
    __shared__ __align__(16) u16 Vs[2][64 * 64];
    const int t = threadIdx.x;
    const int lane15 = t & 15, quad = (t >> 4) & 3, wave = t >> 6;
    const int bh = blockIdx.x;
    const int qt = (int)(gridDim.y - 1) - (int)blockIdx.y;
    const int q0 = qt * 64;
    const int b = bh >> 4, h = bh & 15;
    const u16* Qb = Q  + (size_t)bh * SS * HDIM;
    const u16* Kb = K  + (size_t)bh * SS * HDIM;
    const u16* Vb = Vt + (size_t)bh * HDIM * SS;
    const int kr0 = t >> 3,         ks0 = t & 7;
    const int kr1 = (t + 256) >> 3, ks1 = (t + 256) & 7;
    const int kc0 = ks0 ^ (kr0 & 7);
    const int kc1 = ks1 ^ (kr1 & 7);
    const int ldst = (t & 192) * 8;
    async16(Qb + (size_t)(q0 + kr0) * HDIM + kc0 * 8, QP + ldst);
    async16(Qb + (size_t)(q0 + kr1) * HDIM + kc1 * 8, QP + ldst + 2048);
    async16(Kb + (size_t)kr0 * HDIM + kc0 * 8, &Ks[0][ldst]);
    async16(Kb + (size_t)kr1 * HDIM + kc1 * 8, &Ks[0][ldst + 2048]);
    async16(Vb + (size_t)kr0 * SS + kc0 * 8, &Vs[0][ldst]);
    async16(Vb + (size_t)kr1 * SS + kc1 * 8, &Vs[0][ldst + 2048]);
    const int qrow = wave * 16 + lane15;
    int qoff[2], koff[4][2];
    #pragma unroll
    for (int kh = 0; kh < 2; ++kh)
        qoff[kh] = (qrow * 8 + ((kh * 4 + quad) ^ (qrow & 7))) * 8;
    #pragma unroll
    for (int ni = 0; ni < 4; ++ni)
        #pragma unroll
        for (int kh = 0; kh < 2; ++kh) {
            int row = ni * 16 + lane15;
            koff[ni][kh] = (row * 8 + ((kh * 4 + quad) ^ (row & 7))) * 8;
        }
    __syncthreads();
    bfrag aq[2];
    aq[0] = *(const bfrag*)(QP + qoff[0]);
    aq[1] = *(const bfrag*)(QP + qoff[1]);
    __syncthreads();
    f32x4 acc_o[4];
    float rsum[4] = {0.f, 0.f, 0.f, 0.f};
    #pragma unroll
    for (int nd = 0; nd < 4; ++nd) acc_o[nd] = (f32x4){0.f, 0.f, 0.f, 0.f};
    const int qgb = q0 + wave * 16 + quad * 4;
    for (int kt = 0; kt <= qt; ++kt) {
        if (kt < qt) {
            const int nv0 = (kt + 1) * 64;
            const int pb = (kt + 1) & 1;
            async16(Kb + (size_t)(nv0 + kr0) * HDIM + kc0 * 8, &Ks[pb][ldst]);
            async16(Kb + (size_t)(nv0 + kr1) * HDIM + kc1 * 8, &Ks[pb][ldst + 2048]);
            async16(Vb + (size_t)kr0 * SS + nv0 + kc0 * 8, &Vs[pb][ldst]);
            async16(Vb + (size_t)kr1 * SS + nv0 + kc1 * 8, &Vs[pb][ldst + 2048]);
        }
        const int cb = kt & 1;
        const int kv0 = kt * 64;
        f32x4 s_acc[4];
        #pragma unroll
        for (int ni = 0; ni < 4; ++ni) s_acc[ni] = (f32x4){0.f, 0.f, 0.f, 0.f};
        #pragma unroll
        for (int kh = 0; kh < 2; ++kh)
            #pragma unroll
            for (int ni = 0; ni < 4; ++ni)
                s_acc[ni] = mfma16(aq[kh], *(const bfrag*)&Ks[cb][koff[ni][kh]], s_acc[ni]);
        const bool diag = (kt == qt);
        #pragma unroll
        for (int ni = 0; ni < 4; ++ni) {
            int kvg = kv0 + ni * 16 + lane15;
            #pragma unroll
            for (int r = 0; r < 4; ++r) {
                float v = s_acc[ni][r];
                if (diag && (kvg > qgb + r)) v = NEG_BIG;
                float pw = exp2f(v);
                unsigned pu = __builtin_bit_cast(unsigned, pw);
                rsum[r] += __builtin_bit_cast(float, pu & 0xffff0000u);
                int row = wave * 16 + quad * 4 + r;
                int col = ni * 16 + lane15;
                QP[(row * 8 + ((col >> 3) ^ (row & 7))) * 8 + (col & 7)] = (u16)(pu >> 16);
            }
        }
        #pragma unroll
        for (int kh = 0; kh < 2; ++kh) {
            bfrag ap = *(const bfrag*)(QP + qoff[kh]);
            #pragma unroll
            for (int nd = 0; nd < 4; ++nd)
                acc_o[nd] = mfma16(ap, *(const bfrag*)&Vs[cb][koff[nd][kh]], acc_o[nd]);
        }
        __syncthreads();
    }
    #pragma unroll
    for (int off = 1; off < 16; off <<= 1)
        #pragma unroll
        for (int r = 0; r < 4; ++r)
            rsum[r] += __shfl_xor(rsum[r], off, 64);
    #pragma unroll
    for (int r = 0; r < 4; ++r) {
        float inv = 1.f / rsum[r];
        int srow = q0 + wave * 16 + quad * 4 + r;
        size_t base = ((size_t)b * SS + srow) * DD + h * HDIM;
        #pragma unroll
        for (int nd = 0; nd < 4; ++nd)
            ctx[base + nd * 16 + lane15] = f2u(acc_o[nd][r] * inv);
    }
}

extern "C" void kernel_launch(void* const* d_in, const int* in_sizes, int n_in,
                              void* d_out, int out_size, void* d_ws, size_t ws_size,
                              hipStream_t stream) {
    const float* x  = (const float*)d_in[0];
    const float* wq = (const float*)d_in[1];
    const float* wk = (const float*)d_in[2];
    const float* wv = (const float*)d_in[3];
    const float* wo = (const float*)d_in[4];
    const float* bo = (const float*)d_in[5];
    float* out = (float*)d_out;

    char* ws = (char*)d_ws;
    const size_t MB8 = (size_t)8 * 1024 * 1024;
    u16* xb  = (u16*)(ws);             // 8MB; ctx reuses after qkv consumption
    u16* wT  = (u16*)(ws + MB8);       // 8MB
    u16* Qb  = (u16*)(ws + 2 * MB8);   // 8MB
    u16* Kb  = (u16*)(ws + 3 * MB8);   // 8MB
    u16* Vt  = (u16*)(ws + 4 * MB8);   // 8MB

    int occ = 0;
    hipError_t qe = hipOccupancyMaxActiveBlocksPerMultiprocessor(&occ, (const void*)fused_k, 256, 0);
    if (qe != hipSuccess || occ < 1) occ = 1;
    int grid = occ * 256;
    if (grid > 1024) grid = 1024;

    void* args[] = { (void*)&x, (void*)&wq, (void*)&wk, (void*)&wv, (void*)&wo,
                     (void*)&bo, (void*)&xb, (void*)&wT, (void*)&Qb, (void*)&Kb,
                     (void*)&Vt, (void*)&out };
    hipError_t e = hipLaunchCooperativeKernel((const void*)fused_k, dim3(grid), dim3(256),
                                              args, 0, stream);
    if (e != hipSuccess) {
        // fallback: round-10 four-kernel pipeline
        u16* ctxb = xb;
        prep_k   <<<3072, 256, 0, stream>>>(x, xb, wq, wk, wv, wo, wT);
        gemm_qkv_k<<<dim3(32, 8, 3), 256, 0, stream>>>(xb, wT, Qb, Kb, Vt);
        attn_k   <<<dim3(32, 32), 256, 0, stream>>>(Qb, Kb, Vt, ctxb);
        gemm_out_k<<<dim3(32, 16), 256, 0, stream>>>(ctxb, wT + (size_t)3 * DD * DD, bo, out);
    }
}

// Round 12
// 172.705 us; speedup vs baseline: 2.4099x; 2.4099x over previous
//
#include <hip/hip_runtime.h>
#include <hip/hip_bf16.h>
#include <math.h>

#define BB 2
#define SS 2048
#define DD 1024
#define HH 16
#define HDIM 64

typedef unsigned short u16;
typedef __attribute__((ext_vector_type(8))) short bfrag;   // 8 bf16 = 4 VGPRs
typedef __attribute__((ext_vector_type(4))) float f32x4;

#define NEG_BIG (-1e30f)
// 1/sqrt(64) * log2(e): folded into Q so attention uses exp2 directly
#define QSCALE 0.18033688011112042f

__device__ __forceinline__ u16 f2u(float f) {
    unsigned int u = __builtin_bit_cast(unsigned int, f);
    u += 0x7fffu + ((u >> 16) & 1u);
    return (u16)(u >> 16);
}

__device__ __forceinline__ void async16(const u16* g, u16* l) {
    __builtin_amdgcn_global_load_lds((__attribute__((address_space(1))) void*)g,
                                     (__attribute__((address_space(3))) void*)l,
                                     16, 0, 0);
}

__device__ __forceinline__ f32x4 mfma16(bfrag a, bfrag b, f32x4 c) {
    return __builtin_amdgcn_mfma_f32_16x16x32_bf16(a, b, c, 0, 0, 0);
}

// ---------------------------------------------------------------------------
// prep: fused cvt_x + cvt_wT (unchanged from r10).
// ---------------------------------------------------------------------------
__global__ __launch_bounds__(256) void prep_k(
    const float* __restrict__ x,  u16* __restrict__ xb,
    const float* __restrict__ wq, const float* __restrict__ wk,
    const float* __restrict__ wv, const float* __restrict__ wo,
    u16* __restrict__ wT)
{
    const int id = blockIdx.x;
    const int t = threadIdx.x;
    if (id < 2048) {
        int i = (id * 256 + t) * 8;
        float4 a = *(const float4*)(x + i);
        float4 b = *(const float4*)(x + i + 4);
        u16 o[8] = { f2u(a.x), f2u(a.y), f2u(a.z), f2u(a.w),
                     f2u(b.x), f2u(b.y), f2u(b.z), f2u(b.w) };
        *(uint4*)(xb + i) = *(uint4*)o;
        return;
    }
    const int wid = id - 2048;
    const int z = wid >> 8;
    const int kt = wid & 15, nt = (wid >> 4) & 15;
    const float* w = (z == 0) ? wq : (z == 1) ? wk : (z == 2) ? wv : wo;
    u16* o = wT + (size_t)z * DD * DD;
    __shared__ __align__(16) u16 T[64][72];
    const int k0 = kt * 64, n0 = nt * 64;
    {
        int kr = t >> 2, nb = (t & 3) * 16;
        const float4* s4 = (const float4*)(w + (size_t)(k0 + kr) * DD + n0 + nb);
        #pragma unroll
        for (int jj = 0; jj < 4; ++jj) {
            float4 v = s4[jj];
            T[kr][nb + jj*4 + 0] = f2u(v.x);
            T[kr][nb + jj*4 + 1] = f2u(v.y);
            T[kr][nb + jj*4 + 2] = f2u(v.z);
            T[kr][nb + jj*4 + 3] = f2u(v.w);
        }
    }
    __syncthreads();
    {
        int nr = t >> 2, kb = (t & 3) * 16;
        u16 tmp[16];
        #pragma unroll
        for (int j = 0; j < 16; ++j) tmp[j] = T[kb + j][nr];
        *(uint4*)(o + (size_t)(n0 + nr) * DD + k0 + kb)     = ((uint4*)tmp)[0];
        *(uint4*)(o + (size_t)(n0 + nr) * DD + k0 + kb + 8) = ((uint4*)tmp)[1];
    }
}

// ===========================================================================
// QKV GEMM: BM=128, BN=64, BK=64 -> grid 32x16x3 = 1536 blocks (6/CU by LDS
// 24KB). 16 MFMA/barrier/wave. One head per block -> simple V-transpose.
// Swizzle slot(row,c16)=row*8+(c16^(row&7)).
// ===========================================================================
__global__ __launch_bounds__(256) void gemm_qkv_k(
    const u16* __restrict__ xb, const u16* __restrict__ wT,
    u16* __restrict__ Qo, u16* __restrict__ Ko, u16* __restrict__ Vt)
{
    const u16* wTz = wT + (size_t)blockIdx.z * DD * DD;
    const float osc = (blockIdx.z == 0) ? QSCALE : 1.0f;

    __shared__ __align__(16) u16 As[128 * 64];   // 16 KB
    __shared__ __align__(16) u16 Bs[64 * 64];    // 8 KB

    const int t = threadIdx.x;
    const int m0 = blockIdx.x * 128, n0 = blockIdx.y * 64;
    const int lane15 = t & 15, quad = (t >> 4) & 3, wave = t >> 6;
    const int wm = wave & 1, wn = wave >> 1;

    // A staging: 1024 chunks, 4/thread; B staging: 512 chunks, 2/thread
    int arow[4], acol[4];
    #pragma unroll
    for (int i = 0; i < 4; ++i) {
        int c = t + i * 256;
        arow[i] = c >> 3;
        acol[i] = (c & 7) ^ (arow[i] & 7);
    }
    const int br0 = t >> 3,         bs0 = t & 7;
    const int br1 = (t + 256) >> 3, bs1 = (t + 256) & 7;
    const int bc0 = bs0 ^ (br0 & 7);
    const int bc1 = bs1 ^ (br1 & 7);
    const int ldb = (t & 192) * 8;

    int aoff[4][2], boff[2][2];
    #pragma unroll
    for (int mi = 0; mi < 4; ++mi) {
        int r = wm * 64 + mi * 16 + lane15;
        #pragma unroll
        for (int kh = 0; kh < 2; ++kh)
            aoff[mi][kh] = (r * 8 + ((kh * 4 + quad) ^ (r & 7))) * 8;
    }
    #pragma unroll
    for (int ni = 0; ni < 2; ++ni) {
        int r = wn * 32 + ni * 16 + lane15;
        #pragma unroll
        for (int kh = 0; kh < 2; ++kh)
            boff[ni][kh] = (r * 8 + ((kh * 4 + quad) ^ (r & 7))) * 8;
    }

    f32x4 acc[4][2];
    #pragma unroll
    for (int mi = 0; mi < 4; ++mi)
        #pragma unroll
        for (int ni = 0; ni < 2; ++ni)
            acc[mi][ni] = (f32x4){0.f, 0.f, 0.f, 0.f};

    for (int it = 0; it < 16; ++it) {
        const int k0 = it * 64;
        #pragma unroll
        for (int i = 0; i < 4; ++i)
            async16(xb + (size_t)(m0 + arow[i]) * DD + k0 + acol[i] * 8,
                    As + ldb + i * 2048);
        async16(wTz + (size_t)(n0 + br0) * DD + k0 + bc0 * 8, Bs + ldb);
        async16(wTz + (size_t)(n0 + br1) * DD + k0 + bc1 * 8, Bs + ldb + 2048);
        __syncthreads();
        #pragma unroll
        for (int kh = 0; kh < 2; ++kh) {
            bfrag av[4], bv[2];
            #pragma unroll
            for (int mi = 0; mi < 4; ++mi) av[mi] = *(const bfrag*)(As + aoff[mi][kh]);
            #pragma unroll
            for (int ni = 0; ni < 2; ++ni) bv[ni] = *(const bfrag*)(Bs + boff[ni][kh]);
            #pragma unroll
            for (int mi = 0; mi < 4; ++mi)
                #pragma unroll
                for (int ni = 0; ni < 2; ++ni)
                    acc[mi][ni] = mfma16(av[mi], bv[ni], acc[mi][ni]);
        }
        __syncthreads();
    }

    const int h = n0 >> 6;                   // this block's head
    const int bq = m0 >> 11;                 // batch
    const int ms = m0 & (SS - 1);            // s-base

    if (blockIdx.z != 2) {
        // Q/K: scatter to [B,H,S,HD]
        u16* out = (blockIdx.z == 0) ? Qo : Ko;
        u16* dst = out + (((size_t)(bq * HH + h)) * SS) * HDIM;
        #pragma unroll
        for (int mi = 0; mi < 4; ++mi) {
            #pragma unroll
            for (int r = 0; r < 4; ++r) {
                int s = ms + wm * 64 + mi * 16 + quad * 4 + r;
                #pragma unroll
                for (int ni = 0; ni < 2; ++ni) {
                    int hd = wn * 32 + ni * 16 + lane15;
                    dst[(size_t)s * HDIM + hd] = f2u(acc[mi][ni][r] * osc);
                }
            }
        }
    } else {
        // V: LDS transpose bounce -> Vt[bh][d][s] (one head, all waves)
        u16* T = As;                         // 64 hd x 128 s = 16 KB, swizzled
        __syncthreads();                     // all frag reads done before reuse
        #pragma unroll
        for (int mi = 0; mi < 4; ++mi)
            #pragma unroll
            for (int r = 0; r < 4; ++r) {
                int ml = wm * 64 + mi * 16 + quad * 4 + r;   // s-local 0..127
                #pragma unroll
                for (int ni = 0; ni < 2; ++ni) {
                    int nl = wn * 32 + ni * 16 + lane15;     // hd 0..63
                    T[nl * 128 + (ml ^ ((nl & 7) << 4))] = f2u(acc[mi][ni][r]);
                }
            }
        __syncthreads();
        u16* dst = Vt + ((size_t)(bq * HH + h)) * (HDIM * SS);
        #pragma unroll
        for (int i = 0; i < 4; ++i) {
            int c = t + i * 256;              // 1024 chunks
            int row = c >> 4;                 // hd 0..63
            int mb  = (c & 15) * 8;           // s-chunk base
            uint4 val = *(const uint4*)&T[row * 128 + (mb ^ ((row & 7) << 4))];
            *(uint4*)(dst + (size_t)row * SS + ms + mb) = val;
        }
    }
}

// ---------------------------------------------------------------------------
// Out projection: BM=64, BN=64, BK=64 -> grid 64x16 = 1024 blocks (4+/CU,
// LDS 16KB). 8 MFMA/barrier/wave. Fused bias, fp32 out.
// ---------------------------------------------------------------------------
__global__ __launch_bounds__(256) void gemm_out_k(
    const u16* __restrict__ ctxb, const u16* __restrict__ woT,
    const float* __restrict__ bo, float* __restrict__ out)
{
    __shared__ __align__(16) u16 As[64 * 64];    // 8 KB
    __shared__ __align__(16) u16 Bs[64 * 64];    // 8 KB

    const int t = threadIdx.x;
    const int m0 = blockIdx.x * 64, n0 = blockIdx.y * 64;
    const int lane15 = t & 15, quad = (t >> 4) & 3, wave = t >> 6;
    const int wm = wave & 1, wn = wave >> 1;

    const int br0 = t >> 3,         bs0 = t & 7;
    const int br1 = (t + 256) >> 3, bs1 = (t + 256) & 7;
    const int bc0 = bs0 ^ (br0 & 7);
    const int bc1 = bs1 ^ (br1 & 7);
    const int ldb = (t & 192) * 8;

    int aoff[2][2], boff[2][2];
    #pragma unroll
    for (int mi = 0; mi < 2; ++mi) {
        int r = wm * 32 + mi * 16 + lane15;
        #pragma unroll
        for (int kh = 0; kh < 2; ++kh)
            aoff[mi][kh] = (r * 8 + ((kh * 4 + quad) ^ (r & 7))) * 8;
    }
    #pragma unroll
    for (int ni = 0; ni < 2; ++ni) {
        int r = wn * 32 + ni * 16 + lane15;
        #pragma unroll
        for (int kh = 0; kh < 2; ++kh)
            boff[ni][kh] = (r * 8 + ((kh * 4 + quad) ^ (r & 7))) * 8;
    }

    f32x4 acc[2][2];
    #pragma unroll
    for (int mi = 0; mi < 2; ++mi)
        #pragma unroll
        for (int ni = 0; ni < 2; ++ni)
            acc[mi][ni] = (f32x4){0.f, 0.f, 0.f, 0.f};

    for (int it = 0; it < 16; ++it) {
        const int k0 = it * 64;
        async16(ctxb + (size_t)(m0 + br0) * DD + k0 + bc0 * 8, As + ldb);
        async16(ctxb + (size_t)(m0 + br1) * DD + k0 + bc1 * 8, As + ldb + 2048);
        async16(woT  + (size_t)(n0 + br0) * DD + k0 + bc0 * 8, Bs + ldb);
        async16(woT  + (size_t)(n0 + br1) * DD + k0 + bc1 * 8, Bs + ldb + 2048);
        __syncthreads();
        #pragma unroll
        for (int kh = 0; kh < 2; ++kh) {
            bfrag av[2], bv[2];
            #pragma unroll
            for (int mi = 0; mi < 2; ++mi) av[mi] = *(const bfrag*)(As + aoff[mi][kh]);
            #pragma unroll
            for (int ni = 0; ni < 2; ++ni) bv[ni] = *(const bfrag*)(Bs + boff[ni][kh]);
            #pragma unroll
            for (int mi = 0; mi < 2; ++mi)
                #pragma unroll
                for (int ni = 0; ni < 2; ++ni)
                    acc[mi][ni] = mfma16(av[mi], bv[ni], acc[mi][ni]);
        }
        __syncthreads();
    }

    float bias[2];
    #pragma unroll
    for (int ni = 0; ni < 2; ++ni)
        bias[ni] = bo[n0 + wn * 32 + ni * 16 + lane15];

    #pragma unroll
    for (int mi = 0; mi < 2; ++mi) {
        #pragma unroll
        for (int r = 0; r < 4; ++r) {
            int m = m0 + wm * 32 + mi * 16 + quad * 4 + r;
            #pragma unroll
            for (int ni = 0; ni < 2; ++ni) {
                int n = n0 + wn * 32 + ni * 16 + lane15;
                out[(size_t)m * DD + n] = acc[mi][ni][r] + bias[ni];
            }
        }
    }
}

// ===========================================================================
// MFMA flash attention (r10 verbatim). Fixed-max softmax, exp2, Q-frags in
// registers, Ps aliases Qs, K/V double-buffered, 1 barrier/iter.
// ===========================================================================
__global__ __launch_bounds__(256, 4) void attn_k(
    const u16* __restrict__ Q, const u16* __restrict__ K,
    const u16* __restrict__ Vt, u16* __restrict__ ctx)
{
    __shared__ __align__(16) u16 QP[64 * 64];
    __shared__ __align__(16) u16 Ks[2][64 * 64];
    __shared__ __align__(16) u16 Vs[2][64 * 64];
    const int t = threadIdx.x;
    const int lane15 = t & 15, quad = (t >> 4) & 3, wave = t >> 6;
    const int bh = blockIdx.x;
    const int qt = (int)(gridDim.y - 1) - (int)blockIdx.y;
    const int q0 = qt * 64;
    const int b = bh >> 4, h = bh & 15;
    const u16* Qb = Q  + (size_t)bh * SS * HDIM;
    const u16* Kb = K  + (size_t)bh * SS * HDIM;
    const u16* Vb = Vt + (size_t)bh * HDIM * SS;
    const int kr0 = t >> 3,         ks0 = t & 7;
    const int kr1 = (t + 256) >> 3, ks1 = (t + 256) & 7;
    const int kc0 = ks0 ^ (kr0 & 7);
    const int kc1 = ks1 ^ (kr1 & 7);
    const int ldst = (t & 192) * 8;
    async16(Qb + (size_t)(q0 + kr0) * HDIM + kc0 * 8, QP + ldst);
    async16(Qb + (size_t)(q0 + kr1) * HDIM + kc1 * 8, QP + ldst + 2048);
    async16(Kb + (size_t)kr0 * HDIM + kc0 * 8, &Ks[0][ldst]);
    async16(Kb + (size_t)kr1 * HDIM + kc1 * 8, &Ks[0][ldst + 2048]);
    async16(Vb + (size_t)kr0 * SS + kc0 * 8, &Vs[0][ldst]);
    async16(Vb + (size_t)kr1 * SS + kc1 * 8, &Vs[0][ldst + 2048]);
    const int qrow = wave * 16 + lane15;
    int qoff[2], koff[4][2];
    #pragma unroll
    for (int kh = 0; kh < 2; ++kh)
        qoff[kh] = (qrow * 8 + ((kh * 4 + quad) ^ (qrow & 7))) * 8;
    #pragma unroll
    for (int ni = 0; ni < 4; ++ni)
        #pragma unroll
        for (int kh = 0; kh < 2; ++kh) {
            int row = ni * 16 + lane15;
            koff[ni][kh] = (row * 8 + ((kh * 4 + quad) ^ (row & 7))) * 8;
        }
    __syncthreads();
    bfrag aq[2];
    aq[0] = *(const bfrag*)(QP + qoff[0]);
    aq[1] = *(const bfrag*)(QP + qoff[1]);
    __syncthreads();
    f32x4 acc_o[4];
    float rsum[4] = {0.f, 0.f, 0.f, 0.f};
    #pragma unroll
    for (int nd = 0; nd < 4; ++nd) acc_o[nd] = (f32x4){0.f, 0.f, 0.f, 0.f};
    const int qgb = q0 + wave * 16 + quad * 4;
    for (int kt = 0; kt <= qt; ++kt) {
        if (kt < qt) {
            const int nv0 = (kt + 1) * 64;
            const int pb = (kt + 1) & 1;
            async16(Kb + (size_t)(nv0 + kr0) * HDIM + kc0 * 8, &Ks[pb][ldst]);
            async16(Kb + (size_t)(nv0 + kr1) * HDIM + kc1 * 8, &Ks[pb][ldst + 2048]);
            async16(Vb + (size_t)kr0 * SS + nv0 + kc0 * 8, &Vs[pb][ldst]);
            async16(Vb + (size_t)kr1 * SS + nv0 + kc1 * 8, &Vs[pb][ldst + 2048]);
        }
        const int cb = kt & 1;
        const int kv0 = kt * 64;
        f32x4 s_acc[4];
        #pragma unroll
        for (int ni = 0; ni < 4; ++ni) s_acc[ni] = (f32x4){0.f, 0.f, 0.f, 0.f};
        #pragma unroll
        for (int kh = 0; kh < 2; ++kh)
            #pragma unroll
            for (int ni = 0; ni < 4; ++ni)
                s_acc[ni] = mfma16(aq[kh], *(const bfrag*)&Ks[cb][koff[ni][kh]], s_acc[ni]);
        const bool diag = (kt == qt);
        #pragma unroll
        for (int ni = 0; ni < 4; ++ni) {
            int kvg = kv0 + ni * 16 + lane15;
            #pragma unroll
            for (int r = 0; r < 4; ++r) {
                float v = s_acc[ni][r];
                if (diag && (kvg > qgb + r)) v = NEG_BIG;
                float pw = exp2f(v);
                unsigned pu = __builtin_bit_cast(unsigned, pw);
                rsum[r] += __builtin_bit_cast(float, pu & 0xffff0000u);
                int row = wave * 16 + quad * 4 + r;
                int col = ni * 16 + lane15;
                QP[(row * 8 + ((col >> 3) ^ (row & 7))) * 8 + (col & 7)] = (u16)(pu >> 16);
            }
        }
        #pragma unroll
        for (int kh = 0; kh < 2; ++kh) {
            bfrag ap = *(const bfrag*)(QP + qoff[kh]);
            #pragma unroll
            for (int nd = 0; nd < 4; ++nd)
                acc_o[nd] = mfma16(ap, *(const bfrag*)&Vs[cb][koff[nd][kh]], acc_o[nd]);
        }
        __syncthreads();
    }
    #pragma unroll
    for (int off = 1; off < 16; off <<= 1)
        #pragma unroll
        for (int r = 0; r < 4; ++r)
            rsum[r] += __shfl_xor(rsum[r], off, 64);
    #pragma unroll
    for (int r = 0; r < 4; ++r) {
        float inv = 1.f / rsum[r];
        int srow = q0 + wave * 16 + quad * 4 + r;
        size_t base = ((size_t)b * SS + srow) * DD + h * HDIM;
        #pragma unroll
        for (int nd = 0; nd < 4; ++nd)
            ctx[base + nd * 16 + lane15] = f2u(acc_o[nd][r] * inv);
    }
}

extern "C" void kernel_launch(void* const* d_in, const int* in_sizes, int n_in,
                              void* d_out, int out_size, void* d_ws, size_t ws_size,
                              hipStream_t stream) {
    const float* x  = (const float*)d_in[0];
    const float* wq = (const float*)d_in[1];
    const float* wk = (const float*)d_in[2];
    const float* wv = (const float*)d_in[3];
    const float* wo = (const float*)d_in[4];
    const float* bo = (const float*)d_in[5];
    float* out = (float*)d_out;

    char* ws = (char*)d_ws;
    const size_t MB8 = (size_t)8 * 1024 * 1024;
    u16* xb  = (u16*)(ws);             // 8MB; ctx reuses after qkv consumption
    u16* wT  = (u16*)(ws + MB8);       // 8MB
    u16* Qb  = (u16*)(ws + 2 * MB8);   // 8MB
    u16* Kb  = (u16*)(ws + 3 * MB8);   // 8MB
    u16* Vt  = (u16*)(ws + 4 * MB8);   // 8MB
    u16* ctxb = xb;

    prep_k    <<<3072, 256, 0, stream>>>(x, xb, wq, wk, wv, wo, wT);
    gemm_qkv_k<<<dim3(32, 16, 3), 256, 0, stream>>>(xb, wT, Qb, Kb, Vt);
    attn_k    <<<dim3(32, 32), 256, 0, stream>>>(Qb, Kb, Vt, ctxb);
    gemm_out_k<<<dim3(64, 16), 256, 0, stream>>>(ctxb, wT + (size_t)3 * DD * DD, bo, out);
}